// Round 4
// baseline (191.246 us; speedup 1.0000x reference)
//
#include <hip/hip_runtime.h>

// ---------------------------------------------------------------------------
// Temporal MHA (MI355X/gfx950), B=256, S=176 (8t x 22j), D_in=128, H=8, Hd=32.
//  R11 restructure:
//   k0: W-only transpose/convert (96 blocks). x is NO LONGER pre-converted —
//       the 23MB x fp32 pass, 11.5MB X16 write and 8x re-read are gone.
//   k1 (per (b,h) block, 704 thr = 11 waves):
//    p1: wave w = m-tile w. x fragments loaded as fp32 float4 pairs and packed
//        with v_cvt_pk_bf16_f32 (hw RTNE). W fragments read DIRECTLY from
//        global WT (L2-hot, XCD-co-located) — WS LDS + barrier 0 removed.
//        Q transposed -> regs; K transposed -> KS; V normal -> VT (b64 writes).
//    p2: S^T = K*Q^T, O^T = V^T*P^T via 16x16x32 MFMA with the shared k-slot
//        permutation (verified R5/R7 layouts untouched). exp2-softmax,
//        1/sum folded into epilogue. All bf16 packing via v_cvt_pk_bf16_f32.
//  R8: XCD co-location swizzle (8 heads of a batch share an XCD's L2).
//  R9: KSTRIDE 44 / VSTRIDE 204 bank-spread strides (kept).
//  R10: contiguous-lane K/V epilogues, dword-packed fragments (kept).
// ---------------------------------------------------------------------------

#define SEQ    176
#define HD     32
#define DIN    128
#define DMODEL 256

#define KSTRIDE 44   // KS row stride in ushorts
#define VSTRIDE 204  // VT row stride in ushorts
#define QSCALE  0.25506100344358246f   // (1/sqrt(32)) * log2(e)

typedef unsigned short ushort_t;
typedef unsigned int uint_t;
typedef __attribute__((ext_vector_type(8))) short short8;
typedef __attribute__((ext_vector_type(4))) short short4v;
typedef __attribute__((ext_vector_type(4))) float float4v;
typedef __attribute__((ext_vector_type(2))) unsigned int uint2v;
typedef __attribute__((ext_vector_type(4))) unsigned int uint4v;

// ws layout (bytes): WT bf16 [3][8][32][128] @ 0 (196608 B total)
#define WS_WT 0u

// LDS (ushort units), total 14272 ush = 28544 B
//  KS @ 0     [176][KSTRIDE] = 7744  (K, row-major seq x feat)
//  VT @ 7744  [32][VSTRIDE]  = 6528  (V^T, feat x seq; cols 176..191 zeroed)
#define OFF_VT (176 * KSTRIDE)
#define SMEM_TOTAL (OFF_VT + 32 * VSTRIDE)

// hw packed f32->bf16 (RTNE): dst[15:0]=bf16(a), dst[31:16]=bf16(b)
__device__ __forceinline__ uint_t pk2(float a, float b) {
    uint_t r;
    asm("v_cvt_pk_bf16_f32 %0, %1, %2" : "=v"(r) : "v"(a), "v"(b));
    return r;
}

// ---------------- k0: W transpose + bf16 conversion only ------------------
__global__ __launch_bounds__(256)
void k0_conv(const float* __restrict__ Wq, const float* __restrict__ Wk,
             const float* __restrict__ Wv, ushort_t* __restrict__ WT)
{
    int idx = blockIdx.x * 256 + threadIdx.x;     // < 24576
    int e = idx * 4;
    int mat = e >> 15, h = (e >> 12) & 7, n = (e >> 7) & 31, k = e & 127;
    const float* W = (mat == 0) ? Wq : ((mat == 1) ? Wk : Wv);
    const float sc = (mat == 0) ? QSCALE : 1.0f;  // fold qk scale into Wq
    float w0 = W[(k + 0) * DMODEL + h * HD + n] * sc;
    float w1 = W[(k + 1) * DMODEL + h * HD + n] * sc;
    float w2 = W[(k + 2) * DMODEL + h * HD + n] * sc;
    float w3 = W[(k + 3) * DMODEL + h * HD + n] * sc;
    uint2v o;
    o.x = pk2(w0, w1);
    o.y = pk2(w2, w3);
    reinterpret_cast<uint2v*>(WT)[idx] = o;
}

// ---------------- k1: fused attention -------------------------------------
__global__ __launch_bounds__(704, 6)
void k1_attn(const float* __restrict__ x, const ushort_t* __restrict__ WT,
             const float* __restrict__ bq, const float* __restrict__ bk,
             const float* __restrict__ bv, float* __restrict__ out)
{
    __shared__ __align__(16) ushort_t smem[SMEM_TOTAL];
    ushort_t* KS = smem;                 // [176][KSTRIDE]
    ushort_t* VT = smem + OFF_VT;        // [32][VSTRIDE]

    const int tid  = threadIdx.x;
    const int lane = tid & 63;
    const int w    = tid >> 6;           // wave 0..10 = m-tile / row-tile
    const int c    = lane & 15;
    const int q    = lane >> 4;

    // R8: XCD co-location (bijective, 2048 % 8 == 0)
    const int xcd = blockIdx.x & 7;
    const int j   = blockIdx.x >> 3;
    const int b   = xcd * 32 + (j >> 3);
    const int h   = j & 7;

    // ---- x fragments: fp32 global -> bf16 regs (hw cvt_pk) ---------------
    const float* xrow = x + ((size_t)b * SEQ + w * 16 + c) * DIN + q * 8;
    short8 xf[4];
#pragma unroll
    for (int kk = 0; kk < 4; ++kk) {
        float4 a0 = *reinterpret_cast<const float4*>(xrow + kk * 32);
        float4 a1 = *reinterpret_cast<const float4*>(xrow + kk * 32 + 4);
        union { uint4v u; short8 s; } t;
        t.u = (uint4v){pk2(a0.x, a0.y), pk2(a0.z, a0.w),
                       pk2(a1.x, a1.y), pk2(a1.z, a1.w)};
        xf[kk] = t.s;
    }

    // ---- biases (hoisted) ------------------------------------------------
    float4 bqv0 = *reinterpret_cast<const float4*>(bq + h * HD + q * 4);
    float4 bqv1 = *reinterpret_cast<const float4*>(bq + h * HD + 16 + q * 4);
    bqv0.x *= QSCALE; bqv0.y *= QSCALE; bqv0.z *= QSCALE; bqv0.w *= QSCALE;
    bqv1.x *= QSCALE; bqv1.y *= QSCALE; bqv1.z *= QSCALE; bqv1.w *= QSCALE;
    float4 bkv0 = *reinterpret_cast<const float4*>(bk + h * HD + q * 4);
    float4 bkv1 = *reinterpret_cast<const float4*>(bk + h * HD + 16 + q * 4);
    const float bvc0 = bv[h * HD + c];
    const float bvc1 = bv[h * HD + 16 + c];

    // zero VT pad cols [176,192) (no barrier needed before phase-1 writes;
    // everything is synced by the single barrier below)
    if (tid < 512) {
        VT[(tid >> 4) * VSTRIDE + 176 + (tid & 15)] = 0;
    }

    // ---- phase 1: QKV for m-tile w; W frags direct from global (L2) ------
    // Q transposed (A=W, B=x): lane(c,q) -> Q[t=w*16+c][f=nt*16+q*4+r],
    // pre-scaled via Wq/bq. Packed in permuted k-slot order as dwords.
    uint_t qd[4];
#pragma unroll
    for (int nt = 0; nt < 2; ++nt) {
        const ushort_t* wrow = WT + (size_t)((0 * 8 + h) * 32 + nt * 16 + c) * 128 + q * 8;
        float4v acc = {0.f, 0.f, 0.f, 0.f};
#pragma unroll
        for (int kk = 0; kk < 4; ++kk) {
            short8 wf = *reinterpret_cast<const short8*>(wrow + kk * 32);
            acc = __builtin_amdgcn_mfma_f32_16x16x32_bf16(wf, xf[kk], acc, 0, 0, 0);
        }
        const float4 bb = nt ? bqv1 : bqv0;
        qd[nt * 2 + 0] = pk2(acc[0] + bb.x, acc[1] + bb.y);
        qd[nt * 2 + 1] = pk2(acc[2] + bb.z, acc[3] + bb.w);
    }
    short8 qf8;
    { union { uint4v u; short8 s; } t;
      t.u = (uint4v){qd[0], qd[1], qd[2], qd[3]}; qf8 = t.s; }

    // K TRANSPOSED (A=W, B=x): lane(c,q) -> K[t=w*16+c][d=nt*16+q*4+r].
#pragma unroll
    for (int nt = 0; nt < 2; ++nt) {
        const ushort_t* wrow = WT + (size_t)((1 * 8 + h) * 32 + nt * 16 + c) * 128 + q * 8;
        float4v acc = {0.f, 0.f, 0.f, 0.f};
#pragma unroll
        for (int kk = 0; kk < 4; ++kk) {
            short8 wf = *reinterpret_cast<const short8*>(wrow + kk * 32);
            acc = __builtin_amdgcn_mfma_f32_16x16x32_bf16(wf, xf[kk], acc, 0, 0, 0);
        }
        const float4 bb = nt ? bkv1 : bkv0;
        uint2v kd;
        kd.x = pk2(acc[0] + bb.x, acc[1] + bb.y);
        kd.y = pk2(acc[2] + bb.z, acc[3] + bb.w);
        *reinterpret_cast<uint2v*>(&KS[(w * 16 + c) * KSTRIDE + nt * 16 + q * 4]) = kd;
    }
    // V NORMAL (A=x, B=W) + ReLU: lane(c,q) -> V[t=w*16+q*4+r][d=nt*16+c].
#pragma unroll
    for (int nt = 0; nt < 2; ++nt) {
        const ushort_t* wrow = WT + (size_t)((2 * 8 + h) * 32 + nt * 16 + c) * 128 + q * 8;
        float4v acc = {0.f, 0.f, 0.f, 0.f};
#pragma unroll
        for (int kk = 0; kk < 4; ++kk) {
            short8 wf = *reinterpret_cast<const short8*>(wrow + kk * 32);
            acc = __builtin_amdgcn_mfma_f32_16x16x32_bf16(xf[kk], wf, acc, 0, 0, 0);
        }
        const float bb = nt ? bvc1 : bvc0;
        float v0 = acc[0] + bb; v0 = v0 > 0.f ? v0 : 0.f;
        float v1 = acc[1] + bb; v1 = v1 > 0.f ? v1 : 0.f;
        float v2 = acc[2] + bb; v2 = v2 > 0.f ? v2 : 0.f;
        float v3 = acc[3] + bb; v3 = v3 > 0.f ? v3 : 0.f;
        uint2v vd;
        vd.x = pk2(v0, v1);
        vd.y = pk2(v2, v3);
        *reinterpret_cast<uint2v*>(&VT[(nt * 16 + c) * VSTRIDE + w * 16 + q * 4]) = vd;
    }
    __syncthreads();   // single barrier: KS/VT (+ pad zero) complete

    // ---- phase 2: attention; lane(c,q) owns score column t = w*16+c ----
    const int t_row = w * 16 + c;
    const int lo = (t_row / 22) * 22;
    float su = 0.f;
    uint_t pw[24];                        // P^T fragment dwords (2 per n-tile)
    pw[22] = 0u; pw[23] = 0u;             // n=11 pad half stays zero
#pragma unroll
    for (int n = 0; n < 11; ++n) {
        const ushort_t* krow = KS + (n * 16 + c) * KSTRIDE;
        short4v ka = *reinterpret_cast<const short4v*>(krow + q * 4);
        short4v kb = *reinterpret_cast<const short4v*>(krow + 16 + q * 4);
        short8 kf = {ka.x, ka.y, ka.z, ka.w, kb.x, kb.y, kb.z, kb.w};
        float4v s = {0.f, 0.f, 0.f, 0.f};
        s = __builtin_amdgcn_mfma_f32_16x16x32_bf16(kf, qf8, s, 0, 0, 0);
        float e[4];
#pragma unroll
        for (int r = 0; r < 4; ++r) {
            int tp = n * 16 + q * 4 + r;
            float sv = (((unsigned)(tp - lo) < 22u) && (tp != t_row)) ? -1e30f : s[r];
            e[r] = __builtin_amdgcn_exp2f(sv);
            su += e[r];
        }
        pw[n * 2 + 0] = pk2(e[0], e[1]);
        pw[n * 2 + 1] = pk2(e[2], e[3]);
    }
    su += __shfl_xor(su, 16, 64);
    su += __shfl_xor(su, 32, 64);
    const float invs = 1.0f / su;

    // PV: O^T[d][t] = sum_t' V^T[d][t'] P^T[t'][t]
    float* ob = out + ((size_t)b * SEQ + t_row) * DMODEL + h * HD;
#pragma unroll
    for (int mt = 0; mt < 2; ++mt) {
        const ushort_t* vrow = VT + (mt * 16 + c) * VSTRIDE;
        float4v o = {0.f, 0.f, 0.f, 0.f};
#pragma unroll
        for (int g = 0; g < 6; ++g) {
            short4v va = *reinterpret_cast<const short4v*>(vrow + (2 * g) * 16 + q * 4);
            short4v vb2 = *reinterpret_cast<const short4v*>(vrow + (2 * g + 1) * 16 + q * 4);
            short8 vf = {va.x, va.y, va.z, va.w, vb2.x, vb2.y, vb2.z, vb2.w};
            union { uint4v u; short8 s; } pt;
            pt.u = (uint4v){pw[4 * g], pw[4 * g + 1], pw[4 * g + 2], pw[4 * g + 3]};
            o = __builtin_amdgcn_mfma_f32_16x16x32_bf16(vf, pt.s, o, 0, 0, 0);
        }
        float4 st;
        st.x = o[0] * invs; st.y = o[1] * invs;
        st.z = o[2] * invs; st.w = o[3] * invs;
        *reinterpret_cast<float4*>(ob + mt * 16 + q * 4) = st;
    }
}

extern "C" void kernel_launch(void* const* d_in, const int* in_sizes, int n_in,
                              void* d_out, int out_size, void* d_ws, size_t ws_size,
                              hipStream_t stream) {
    const float* x  = (const float*)d_in[0];
    const float* Wq = (const float*)d_in[1];
    const float* bq = (const float*)d_in[2];
    const float* Wk = (const float*)d_in[3];
    const float* bk = (const float*)d_in[4];
    const float* Wv = (const float*)d_in[5];
    const float* bv = (const float*)d_in[6];
    float* out = (float*)d_out;

    char* ws = (char*)d_ws;
    ushort_t* WT = (ushort_t*)(ws + WS_WT);

    k0_conv<<<dim3(96), dim3(256), 0, stream>>>(Wq, Wk, Wv, WT);
    k1_attn<<<dim3(2048), dim3(704), 0, stream>>>(x, WT, bq, bk, bv, out);
}

// Round 5
// 131.510 us; speedup vs baseline: 1.4542x; 1.4542x over previous
//
#include <hip/hip_runtime.h>

// ---------------------------------------------------------------------------
// Temporal MHA (MI355X/gfx950), B=256, S=176 (8t x 22j), D_in=128, H=8, Hd=32.
//  R12 = R10 structure + R11's verified wins, R11's regression reverted:
//   k0: W-only transpose/convert (96 blocks). x never pre-converted.
//   k1 (per (b,h) block, 704 thr = 11 waves):
//    p0: x fragments loaded fp32 (hoisted, latency hidden under staging) and
//        packed via v_cvt_pk_bf16_f32. W slices staged to WS LDS (restored —
//        R11 proved direct-global W frags are latency-fatal: k1 55->117us).
//    p1: Q transposed -> regs; K transposed -> KS; V normal -> VT (b64 writes,
//        contiguous lane outputs, hw cvt_pk packing).
//    p2: S^T = K*Q^T, O^T = V^T*P^T via 16x16x32 MFMA with the shared k-slot
//        permutation; exp2-softmax, 1/sum in epilogue.
//  R8: XCD co-location swizzle. R9: KSTRIDE 44 / VSTRIDE 204.
//  Known-benign: ~2.2M SQ_LDS_BANK_CONFLICT from WS phase-1 reads (~3.6us
//  total, measured R10 vs R11 delta) — do not chase.
// ---------------------------------------------------------------------------

#define SEQ    176
#define HD     32
#define DIN    128
#define DMODEL 256

#define KSTRIDE 44   // KS row stride in ushorts
#define VSTRIDE 204  // VT row stride in ushorts
#define QSCALE  0.25506100344358246f   // (1/sqrt(32)) * log2(e)

typedef unsigned short ushort_t;
typedef unsigned int uint_t;
typedef __attribute__((ext_vector_type(8))) short short8;
typedef __attribute__((ext_vector_type(4))) short short4v;
typedef __attribute__((ext_vector_type(4))) float float4v;
typedef __attribute__((ext_vector_type(2))) unsigned int uint2v;
typedef __attribute__((ext_vector_type(4))) unsigned int uint4v;

// ws layout (bytes): WT bf16 [3][8][32][128] @ 0 (196608 B total)
#define WS_WT 0u

// LDS (ushort units), total 27328 ush = 54656 B
//  WS @ 0      [3][32][136]    = 13056  (phase 1 W slices, padded)
//  KS @ 13056  [176][KSTRIDE]  = 7744   (K, row-major seq x feat)
//  VT @ 20800  [32][VSTRIDE]   = 6528   (V^T, feat x seq; cols 176..191 zeroed)
#define OFF_KS 13056
#define OFF_VT (OFF_KS + 176 * KSTRIDE)
#define SMEM_TOTAL (OFF_VT + 32 * VSTRIDE)

// hw packed f32->bf16 (RTNE): dst[15:0]=bf16(a), dst[31:16]=bf16(b)
__device__ __forceinline__ uint_t pk2(float a, float b) {
    uint_t r;
    asm("v_cvt_pk_bf16_f32 %0, %1, %2" : "=v"(r) : "v"(a), "v"(b));
    return r;
}

// ---------------- k0: W transpose + bf16 conversion only ------------------
__global__ __launch_bounds__(256)
void k0_conv(const float* __restrict__ Wq, const float* __restrict__ Wk,
             const float* __restrict__ Wv, ushort_t* __restrict__ WT)
{
    int idx = blockIdx.x * 256 + threadIdx.x;     // < 24576
    int e = idx * 4;
    int mat = e >> 15, h = (e >> 12) & 7, n = (e >> 7) & 31, k = e & 127;
    const float* W = (mat == 0) ? Wq : ((mat == 1) ? Wk : Wv);
    const float sc = (mat == 0) ? QSCALE : 1.0f;  // fold qk scale into Wq
    float w0 = W[(k + 0) * DMODEL + h * HD + n] * sc;
    float w1 = W[(k + 1) * DMODEL + h * HD + n] * sc;
    float w2 = W[(k + 2) * DMODEL + h * HD + n] * sc;
    float w3 = W[(k + 3) * DMODEL + h * HD + n] * sc;
    uint2v o;
    o.x = pk2(w0, w1);
    o.y = pk2(w2, w3);
    reinterpret_cast<uint2v*>(WT)[idx] = o;
}

// ---------------- k1: fused attention -------------------------------------
__global__ __launch_bounds__(704, 6)
void k1_attn(const float* __restrict__ x, const ushort_t* __restrict__ WT,
             const float* __restrict__ bq, const float* __restrict__ bk,
             const float* __restrict__ bv, float* __restrict__ out)
{
    __shared__ __align__(16) ushort_t smem[SMEM_TOTAL];
    ushort_t* WS = smem;                 // [3][32][136]
    ushort_t* KS = smem + OFF_KS;        // [176][KSTRIDE]
    ushort_t* VT = smem + OFF_VT;        // [32][VSTRIDE]

    const int tid  = threadIdx.x;
    const int lane = tid & 63;
    const int w    = tid >> 6;           // wave 0..10 = m-tile / row-tile
    const int c    = lane & 15;
    const int q    = lane >> 4;

    // R8: XCD co-location (bijective, 2048 % 8 == 0)
    const int xcd = blockIdx.x & 7;
    const int j   = blockIdx.x >> 3;
    const int b   = xcd * 32 + (j >> 3);
    const int h   = j & 7;

    // ---- hoisted x loads (fp32) — latency hides under W staging ----------
    const float* xrow = x + ((size_t)b * SEQ + w * 16 + c) * DIN + q * 8;
    float4 xa[4][2];
#pragma unroll
    for (int kk = 0; kk < 4; ++kk) {
        xa[kk][0] = *reinterpret_cast<const float4*>(xrow + kk * 32);
        xa[kk][1] = *reinterpret_cast<const float4*>(xrow + kk * 32 + 4);
    }

    // ---- biases (hoisted) ------------------------------------------------
    float4 bqv0 = *reinterpret_cast<const float4*>(bq + h * HD + q * 4);
    float4 bqv1 = *reinterpret_cast<const float4*>(bq + h * HD + 16 + q * 4);
    bqv0.x *= QSCALE; bqv0.y *= QSCALE; bqv0.z *= QSCALE; bqv0.w *= QSCALE;
    bqv1.x *= QSCALE; bqv1.y *= QSCALE; bqv1.z *= QSCALE; bqv1.w *= QSCALE;
    float4 bkv0 = *reinterpret_cast<const float4*>(bk + h * HD + q * 4);
    float4 bkv1 = *reinterpret_cast<const float4*>(bk + h * HD + 16 + q * 4);
    const float bvc0 = bv[h * HD + c];
    const float bvc1 = bv[h * HD + 16 + c];

    // ---- stage W-slice (head h): 1536 chunks of 16 B ---------------------
#pragma unroll
    for (int it = 0; it < 3; ++it) {
        int c8 = tid + it * 704;
        if (c8 < 1536) {
            int mat = c8 >> 9, rem = c8 & 511, n = rem >> 4, kc = rem & 15;
            short8 v = *reinterpret_cast<const short8*>(
                WT + (size_t)(((mat * 8 + h) * 32 + n) * 128 + kc * 8));
            *reinterpret_cast<short8*>(WS + (mat * 32 + n) * 136 + kc * 8) = v;
        }
    }
    // zero VT pad cols [176,192)
    if (tid < 512) {
        VT[(tid >> 4) * VSTRIDE + 176 + (tid & 15)] = 0;
    }

    // ---- pack x to bf16 while staging's ds/vm traffic drains -------------
    short8 xf[4];
#pragma unroll
    for (int kk = 0; kk < 4; ++kk) {
        union { uint4v u; short8 s; } t;
        t.u = (uint4v){pk2(xa[kk][0].x, xa[kk][0].y), pk2(xa[kk][0].z, xa[kk][0].w),
                       pk2(xa[kk][1].x, xa[kk][1].y), pk2(xa[kk][1].z, xa[kk][1].w)};
        xf[kk] = t.s;
    }
    __syncthreads();   // barrier 0: W staging complete

    // ---- phase 1: QKV for m-tile w ---------------------------------------
    // Q transposed (A=W, B=x): lane(c,q) -> Q[t=w*16+c][f=nt*16+q*4+r].
    uint_t qd[4];
#pragma unroll
    for (int nt = 0; nt < 2; ++nt) {
        const ushort_t* wrow = WS + (nt * 16 + c) * 136 + q * 8;
        float4v acc = {0.f, 0.f, 0.f, 0.f};
#pragma unroll
        for (int kk = 0; kk < 4; ++kk) {
            short8 wf = *reinterpret_cast<const short8*>(wrow + kk * 32);
            acc = __builtin_amdgcn_mfma_f32_16x16x32_bf16(wf, xf[kk], acc, 0, 0, 0);
        }
        const float4 bb = nt ? bqv1 : bqv0;
        qd[nt * 2 + 0] = pk2(acc[0] + bb.x, acc[1] + bb.y);
        qd[nt * 2 + 1] = pk2(acc[2] + bb.z, acc[3] + bb.w);
    }
    short8 qf8;
    { union { uint4v u; short8 s; } t;
      t.u = (uint4v){qd[0], qd[1], qd[2], qd[3]}; qf8 = t.s; }

    // K TRANSPOSED (A=W, B=x): lane(c,q) -> K[t=w*16+c][d=nt*16+q*4+r].
#pragma unroll
    for (int nt = 0; nt < 2; ++nt) {
        const ushort_t* wrow = WS + (32 + nt * 16 + c) * 136 + q * 8;
        float4v acc = {0.f, 0.f, 0.f, 0.f};
#pragma unroll
        for (int kk = 0; kk < 4; ++kk) {
            short8 wf = *reinterpret_cast<const short8*>(wrow + kk * 32);
            acc = __builtin_amdgcn_mfma_f32_16x16x32_bf16(wf, xf[kk], acc, 0, 0, 0);
        }
        const float4 bb = nt ? bkv1 : bkv0;
        uint2v kd;
        kd.x = pk2(acc[0] + bb.x, acc[1] + bb.y);
        kd.y = pk2(acc[2] + bb.z, acc[3] + bb.w);
        *reinterpret_cast<uint2v*>(&KS[(w * 16 + c) * KSTRIDE + nt * 16 + q * 4]) = kd;
    }
    // V NORMAL (A=x, B=W) + ReLU: lane(c,q) -> V[t=w*16+q*4+r][d=nt*16+c].
#pragma unroll
    for (int nt = 0; nt < 2; ++nt) {
        const ushort_t* wrow = WS + (64 + nt * 16 + c) * 136 + q * 8;
        float4v acc = {0.f, 0.f, 0.f, 0.f};
#pragma unroll
        for (int kk = 0; kk < 4; ++kk) {
            short8 wf = *reinterpret_cast<const short8*>(wrow + kk * 32);
            acc = __builtin_amdgcn_mfma_f32_16x16x32_bf16(xf[kk], wf, acc, 0, 0, 0);
        }
        const float bb = nt ? bvc1 : bvc0;
        float v0 = acc[0] + bb; v0 = v0 > 0.f ? v0 : 0.f;
        float v1 = acc[1] + bb; v1 = v1 > 0.f ? v1 : 0.f;
        float v2 = acc[2] + bb; v2 = v2 > 0.f ? v2 : 0.f;
        float v3 = acc[3] + bb; v3 = v3 > 0.f ? v3 : 0.f;
        uint2v vd;
        vd.x = pk2(v0, v1);
        vd.y = pk2(v2, v3);
        *reinterpret_cast<uint2v*>(&VT[(nt * 16 + c) * VSTRIDE + w * 16 + q * 4]) = vd;
    }
    __syncthreads();   // barrier 1: KS/VT complete

    // ---- phase 2: attention; lane(c,q) owns score column t = w*16+c ----
    const int t_row = w * 16 + c;
    const int lo = (t_row / 22) * 22;
    float su = 0.f;
    uint_t pw[24];                        // P^T fragment dwords (2 per n-tile)
    pw[22] = 0u; pw[23] = 0u;             // n=11 pad half stays zero
#pragma unroll
    for (int n = 0; n < 11; ++n) {
        const ushort_t* krow = KS + (n * 16 + c) * KSTRIDE;
        short4v ka = *reinterpret_cast<const short4v*>(krow + q * 4);
        short4v kb = *reinterpret_cast<const short4v*>(krow + 16 + q * 4);
        short8 kf = {ka.x, ka.y, ka.z, ka.w, kb.x, kb.y, kb.z, kb.w};
        float4v s = {0.f, 0.f, 0.f, 0.f};
        s = __builtin_amdgcn_mfma_f32_16x16x32_bf16(kf, qf8, s, 0, 0, 0);
        float e[4];
#pragma unroll
        for (int r = 0; r < 4; ++r) {
            int tp = n * 16 + q * 4 + r;
            float sv = (((unsigned)(tp - lo) < 22u) && (tp != t_row)) ? -1e30f : s[r];
            e[r] = __builtin_amdgcn_exp2f(sv);
            su += e[r];
        }
        pw[n * 2 + 0] = pk2(e[0], e[1]);
        pw[n * 2 + 1] = pk2(e[2], e[3]);
    }
    su += __shfl_xor(su, 16, 64);
    su += __shfl_xor(su, 32, 64);
    const float invs = 1.0f / su;

    // PV: O^T[d][t] = sum_t' V^T[d][t'] P^T[t'][t]
    float* ob = out + ((size_t)b * SEQ + t_row) * DMODEL + h * HD;
#pragma unroll
    for (int mt = 0; mt < 2; ++mt) {
        const ushort_t* vrow = VT + (mt * 16 + c) * VSTRIDE;
        float4v o = {0.f, 0.f, 0.f, 0.f};
#pragma unroll
        for (int g = 0; g < 6; ++g) {
            short4v va = *reinterpret_cast<const short4v*>(vrow + (2 * g) * 16 + q * 4);
            short4v vb2 = *reinterpret_cast<const short4v*>(vrow + (2 * g + 1) * 16 + q * 4);
            short8 vf = {va.x, va.y, va.z, va.w, vb2.x, vb2.y, vb2.z, vb2.w};
            union { uint4v u; short8 s; } pt;
            pt.u = (uint4v){pw[4 * g], pw[4 * g + 1], pw[4 * g + 2], pw[4 * g + 3]};
            o = __builtin_amdgcn_mfma_f32_16x16x32_bf16(vf, pt.s, o, 0, 0, 0);
        }
        float4 st;
        st.x = o[0] * invs; st.y = o[1] * invs;
        st.z = o[2] * invs; st.w = o[3] * invs;
        *reinterpret_cast<float4*>(ob + mt * 16 + q * 4) = st;
    }
}

extern "C" void kernel_launch(void* const* d_in, const int* in_sizes, int n_in,
                              void* d_out, int out_size, void* d_ws, size_t ws_size,
                              hipStream_t stream) {
    const float* x  = (const float*)d_in[0];
    const float* Wq = (const float*)d_in[1];
    const float* bq = (const float*)d_in[2];
    const float* Wk = (const float*)d_in[3];
    const float* bk = (const float*)d_in[4];
    const float* Wv = (const float*)d_in[5];
    const float* bv = (const float*)d_in[6];
    float* out = (float*)d_out;

    char* ws = (char*)d_ws;
    ushort_t* WT = (ushort_t*)(ws + WS_WT);

    k0_conv<<<dim3(96), dim3(256), 0, stream>>>(Wq, Wk, Wv, WT);
    k1_attn<<<dim3(2048), dim3(704), 0, stream>>>(x, WT, bq, bk, bv, out);
}